// Round 6
// baseline (65.857 us; speedup 1.0000x reference)
//
#include <hip/hip_runtime.h>
#include <math.h>

#define Bsz 4096
#define Dk 128
#define RPB 16                   // rows per block (full-row blocks)
#define NBLK (Bsz / RPB)         // 256 blocks = 1 per CU
#define THREADS 1024             // 16 waves
#define NW 16

typedef __attribute__((ext_vector_type(8))) short short8;
typedef __attribute__((ext_vector_type(4))) float f32x4;
typedef _Float16 half8 __attribute__((ext_vector_type(8)));
typedef _Float16 half4 __attribute__((ext_vector_type(4)));

__device__ __forceinline__ unsigned short f2bf(float f) {
  unsigned u = __float_as_uint(f);
  u = (u + 0x7fffu + ((u >> 16) & 1u)) >> 16;   // RNE
  return (unsigned short)u;
}

// X fp32 -> bf16, one shot; also zeroes the 33 atomic cells (every launch:
// the fused kernel's atomics accumulate and ws is never re-poisoned).
__global__ __launch_bounds__(256)
void convert_kernel(const float* __restrict__ X, short* __restrict__ Xb,
                    unsigned long long* __restrict__ cells) {
  int i = blockIdx.x * 256 + threadIdx.x;     // 65536 threads x 8 elems
  if (i < 33) cells[i] = 0ull;                // [0..15]=sum_fx [16..31]=cnt [32]=done
  const float4* q = (const float4*)X + i * 2;
  float4 v0 = q[0], v1 = q[1];
  short8 r;
  r[0] = (short)f2bf(v0.x); r[1] = (short)f2bf(v0.y);
  r[2] = (short)f2bf(v0.z); r[3] = (short)f2bf(v0.w);
  r[4] = (short)f2bf(v1.x); r[5] = (short)f2bf(v1.y);
  r[6] = (short)f2bf(v1.z); r[7] = (short)f2bf(v1.w);
  ((short8*)Xb)[i] = r;
}

// Fused: block = 16 rows x 4096 cols. GEMM -> sim in LDS (fp16, [col][row]),
// row min/max block-local, exp pass from LDS, block loss -> exact fixed-point
// atomics; last finished block writes the mean. No global sim traffic.
__global__ __launch_bounds__(THREADS)
void fused(const short* __restrict__ Xb, const int* __restrict__ labels,
           unsigned long long* __restrict__ cells, float* __restrict__ out) {
  const int t  = threadIdx.x;
  const int w  = t >> 6;
  const int l  = t & 63;
  const int lg = l >> 4;      // C row-group
  const int lr = l & 15;      // B/C col-in-tile, A row-in-tile
  const int r0 = blockIdx.x * RPB;

  __shared__ __align__(16) _Float16 tile[Bsz][RPB];   // 128 KB, [col][row]
  __shared__ float red0[NW][RPB], red1[NW][RPB];      // wave partials (reused)
  __shared__ float thrp[RPB], thrn[RPB], thrx[RPB];
  __shared__ int   labl[RPB];

  if (t < RPB) labl[t] = labels[r0 + t];

  // A fragments: this block's 16 rows x K=128 (16 VGPR), same for all waves.
  short8 afrag[4];
  {
    const short* ap = Xb + (r0 + lr) * Dk + lg * 8;
    for (int ks = 0; ks < 4; ++ks) afrag[ks] = *(const short8*)(ap + ks * 32);
  }
  int labr[4];
  for (int rg = 0; rg < 4; ++rg) labr[rg] = labels[r0 + lg * 4 + rg];

  float mn[4], mx[4];
  for (int rg = 0; rg < 4; ++rg) { mn[rg] = INFINITY; mx[rg] = -INFINITY; }

  // ---- phase 1: GEMM over this wave's 256 cols (16 col-tiles) ----
#pragma unroll 4
  for (int ct = 0; ct < 16; ++ct) {
    const int colv = (w << 8) + (ct << 4) + lr;
    short8 bfrag[4];
    {
      const short* bp = Xb + colv * Dk + lg * 8;
      for (int ks = 0; ks < 4; ++ks) bfrag[ks] = *(const short8*)(bp + ks * 32);
    }
    const int labc = labels[colv];

    f32x4 acc = {0.f, 0.f, 0.f, 0.f};
    for (int ks = 0; ks < 4; ++ks)
      acc = __builtin_amdgcn_mfma_f32_16x16x32_bf16(afrag[ks], bfrag[ks], acc, 0, 0, 0);

    half4 hv;
    // C/D layout (verified): col = lane&15, row = (lane>>4)*4 + reg
    for (int rg = 0; rg < 4; ++rg) {
      float v    = acc[rg];
      bool  eq   = (labc == labr[rg]);
      bool  self = (colv == r0 + lg * 4 + rg);
      if (eq && !self) mn[rg] = fminf(mn[rg], v);
      if (!eq)         mx[rg] = fmaxf(mx[rg], v);
      hv[rg] = (_Float16)v;
    }
    *(half4*)&tile[colv][lg * 4] = hv;   // 8B aligned transposed store
  }

  // min/max across the 16 col-lanes sharing each row (stays within lg group)
  for (int rg = 0; rg < 4; ++rg) {
    for (int m = 1; m < 16; m <<= 1) {
      mn[rg] = fminf(mn[rg], __shfl_xor(mn[rg], m, 64));
      mx[rg] = fmaxf(mx[rg], __shfl_xor(mx[rg], m, 64));
    }
  }
  if (lr == 0)
    for (int rg = 0; rg < 4; ++rg) {
      red0[w][lg * 4 + rg] = mn[rg];
      red1[w][lg * 4 + rg] = mx[rg];
    }
  __syncthreads();

  if (t < RPB) {
    float a = INFINITY, b = -INFINITY;
    for (int ww = 0; ww < NW; ++ww) {
      a = fminf(a, red0[ww][t]);
      b = fmaxf(b, red1[ww][t]);
    }
    thrn[t] = a - 0.1f;   // neg_keep: v > min_pos - 0.1
    thrp[t] = b + 0.1f;   // pos_keep: v < max_neg + 0.1
    thrx[t] = b;          // raw max_neg (exact validity check)
  }
  __syncthreads();

  // ---- phase 2: exp sums from LDS ----
  float tp[RPB], tn[RPB];
  int   lb[RPB];
  for (int r = 0; r < RPB; ++r) { tp[r] = thrp[r]; tn[r] = thrn[r]; lb[r] = labl[r]; }

  float apr[RPB], anr[RPB];
  for (int r = 0; r < RPB; ++r) { apr[r] = 0.f; anr[r] = 0.f; }

#pragma unroll
  for (int cc = 0; cc < 4; ++cc) {
    const int c    = t + cc * THREADS;
    const int labc = labels[c];
    half8 h0 = *(const half8*)&tile[c][0];
    half8 h8 = *(const half8*)&tile[c][8];
#pragma unroll
    for (int r = 0; r < RPB; ++r) {
      float v    = (float)((r < 8) ? h0[r] : h8[r - 8]);
      bool  eq   = (labc == lb[r]);
      bool  self = (c == r0 + r);
      bool  kp   = eq && !self && (v < tp[r]);
      bool  kn   = (!eq) && (v > tn[r]);
      float argp = fmaf(v, -2.885390082f, 1.442695041f);   // -2*(v-0.5)*log2e
      float argn = fmaf(v, 57.70780163f, -28.85390082f);   // 40*(v-0.5)*log2e
      float e = exp2f(kp ? argp : argn);
      apr[r] += kp ? e : 0.f;
      anr[r] += kn ? e : 0.f;
    }
  }
  // wave reduce each row sum, then cross-wave via LDS (red arrays reused)
  for (int r = 0; r < RPB; ++r) {
    for (int m = 1; m < 64; m <<= 1) {
      apr[r] += __shfl_xor(apr[r], m, 64);
      anr[r] += __shfl_xor(anr[r], m, 64);
    }
  }
  if (l == 0)
    for (int r = 0; r < RPB; ++r) { red0[w][r] = apr[r]; red1[w][r] = anr[r]; }
  __syncthreads();

  // ---- block epilogue: 16 row losses -> one fixed-point atomic ----
  if (w == 0) {
    float loss = 0.f, cnt = 0.f;
    if (t < RPB) {
      float P = 0.f, N = 0.f;
      for (int ww = 0; ww < NW; ++ww) { P += red0[ww][t]; N += red1[ww][t]; }
      bool valid = (thrn[t] < thrx[t]);   // min_pos - 0.1 < max_neg
      loss = valid ? (log1pf(P) * 0.5f + log1pf(N) * 0.025f) : 0.f;
      cnt  = valid ? 1.f : 0.f;
    }
    for (int m = 1; m < 64; m <<= 1) {
      loss += __shfl_xor(loss, m, 64);
      cnt  += __shfl_xor(cnt,  m, 64);
    }
    if (t == 0) {
      unsigned long long fx = (unsigned long long)(loss * 1099511627776.0f); // 2^40
      atomicAdd(&cells[blockIdx.x & 15], fx);
      atomicAdd(&cells[16 + (blockIdx.x & 15)], (unsigned long long)(int)cnt);
      __threadfence();
      unsigned long long old = atomicAdd(&cells[32], 1ull);
      if (old == (unsigned long long)(gridDim.x - 1)) {   // last block finalizes
        unsigned long long S = 0ull, C = 0ull;
        for (int i = 0; i < 16; ++i) {
          S += atomicAdd(&cells[i], 0ull);
          C += atomicAdd(&cells[16 + i], 0ull);
        }
        out[0] = (float)((double)S / 1099511627776.0 / (double)(C ? C : 1ull));
      }
    }
  }
}

extern "C" void kernel_launch(void* const* d_in, const int* in_sizes, int n_in,
                              void* d_out, int out_size, void* d_ws, size_t ws_size,
                              hipStream_t stream) {
  const float* X      = (const float*)d_in[0];
  const int*   labels = (const int*)d_in[1];

  char* ws = (char*)d_ws;
  short*              Xb    = (short*)ws;                        // 1 MB
  unsigned long long* cells = (unsigned long long*)(ws + 1048576);

  convert_kernel<<<256, 256, 0, stream>>>(X, Xb, cells);
  fused<<<NBLK, THREADS, 0, stream>>>(Xb, labels, cells, (float*)d_out);
}